// Round 9
// baseline (247.998 us; speedup 1.0000x reference)
//
#include <hip/hip_runtime.h>
#include <stdint.h>

#define BATCH 8
#define NN 4096
#define CC 64
#define MASKV -1.0e30f
#define LOG2E 1.4426950408889634f

typedef _Float16 half8 __attribute__((ext_vector_type(8)));
typedef _Float16 half4 __attribute__((ext_vector_type(4)));
typedef __fp16 fp16x2 __attribute__((ext_vector_type(2)));
typedef float f32x4 __attribute__((ext_vector_type(4)));
typedef float f32x16 __attribute__((ext_vector_type(16)));

__device__ __forceinline__ unsigned pk_rtz(float a, float b) {
    union { fp16x2 h; unsigned u; } r;
    r.h = __builtin_amdgcn_cvt_pkrtz(a, b);
    return r.u;
}

// ------------------------------------------------------------------
// Fused prep: blocks 0-511 = projection (q fp16 pre-scaled by log2e,
// k fp16, vT fp16 [b][c][n]; split-compensated fp16 MFMA); blocks
// 512-4607 = adjacency bitmask (forced diagonal, compact 2 MB).
// ------------------------------------------------------------------
__global__ __launch_bounds__(256) void gat_prep(
    const float* __restrict__ X, const float* __restrict__ W0,
    const float* __restrict__ Wq, const float* __restrict__ Wk,
    const int* __restrict__ A,
    _Float16* __restrict__ qh, _Float16* __restrict__ kb,
    _Float16* __restrict__ vt, unsigned short* __restrict__ M16)
{
    __shared__ alignas(16) _Float16 WTh[3][64][72];
    __shared__ alignas(16) _Float16 WTl[3][64][72];
    const int t = threadIdx.x;
    if (blockIdx.x >= 512) {                       // ---- mask part
        const int row = blockIdx.x - 512;
        const int4* ap = (const int4*)(A + (size_t)row * NN + t * 16);
        unsigned m = 0;
        #pragma unroll
        for (int j = 0; j < 4; ++j) {
            int4 a = ap[j];
            m |= (a.x != 0 ? 1u : 0u) << (4*j);
            m |= (a.y != 0 ? 1u : 0u) << (4*j + 1);
            m |= (a.z != 0 ? 1u : 0u) << (4*j + 2);
            m |= (a.w != 0 ? 1u : 0u) << (4*j + 3);
        }
        if (t == (row >> 4)) m |= 1u << (row & 15);
        M16[(size_t)row * 256 + t] = (unsigned short)m;
        return;
    }
    // ---- projection part
    const float* Ws[3] = {W0, Wq, Wk};
    for (int e = t; e < 4096; e += 256) {
        int k = e >> 6, c = e & 63;
        #pragma unroll
        for (int m = 0; m < 3; ++m) {
            float w = Ws[m][e];
            _Float16 hi = (_Float16)w;
            WTh[m][c][k] = hi;
            WTl[m][c][k] = (_Float16)(w - (float)hi);
        }
    }
    __syncthreads();
    const int lane = t & 63, wv = t >> 6;
    const int cl = lane & 15, g = lane >> 4;
    int tile = blockIdx.x * 4 + wv;
    int gr = tile * 16;
    const float* xr = X + (size_t)(gr + cl) * CC;
    half8 xh[2], xl[2];
    #pragma unroll
    for (int kf = 0; kf < 2; ++kf) {
        f32x4 a0 = *(const f32x4*)(xr + g*8 + kf*32);
        f32x4 a1 = *(const f32x4*)(xr + g*8 + kf*32 + 4);
        half8 h, l;
        #pragma unroll
        for (int j = 0; j < 4; ++j) {
            _Float16 h0 = (_Float16)a0[j], h1 = (_Float16)a1[j];
            h[j]   = h0; l[j]   = (_Float16)(a0[j] - (float)h0);
            h[j+4] = h1; l[j+4] = (_Float16)(a1[j] - (float)h1);
        }
        xh[kf] = h; xl[kf] = l;
    }
    #pragma unroll
    for (int mat = 1; mat <= 2; ++mat) {
        #pragma unroll
        for (int nt = 0; nt < 4; ++nt) {
            f32x4 acc = {0.f, 0.f, 0.f, 0.f};
            #pragma unroll
            for (int kf = 0; kf < 2; ++kf) {
                half8 bh = *(const half8*)&WTh[mat][nt*16 + cl][g*8 + kf*32];
                half8 bl = *(const half8*)&WTl[mat][nt*16 + cl][g*8 + kf*32];
                acc = __builtin_amdgcn_mfma_f32_16x16x32_f16(xh[kf], bh, acc, 0, 0, 0);
                acc = __builtin_amdgcn_mfma_f32_16x16x32_f16(xl[kf], bh, acc, 0, 0, 0);
                acc = __builtin_amdgcn_mfma_f32_16x16x32_f16(xh[kf], bl, acc, 0, 0, 0);
            }
            #pragma unroll
            for (int i = 0; i < 4; ++i) {
                size_t off = (size_t)(gr + 4*g + i) * CC + nt*16 + cl;
                if (mat == 1) qh[off] = (_Float16)(acc[i] * LOG2E);
                else          kb[off] = (_Float16)acc[i];
            }
        }
    }
    {
        int b = gr >> 12, n0 = gr & (NN - 1);
        #pragma unroll
        for (int mt = 0; mt < 4; ++mt) {
            f32x4 acc = {0.f, 0.f, 0.f, 0.f};
            #pragma unroll
            for (int kf = 0; kf < 2; ++kf) {
                half8 ah = *(const half8*)&WTh[0][mt*16 + cl][g*8 + kf*32];
                half8 al = *(const half8*)&WTl[0][mt*16 + cl][g*8 + kf*32];
                acc = __builtin_amdgcn_mfma_f32_16x16x32_f16(ah, xh[kf], acc, 0, 0, 0);
                acc = __builtin_amdgcn_mfma_f32_16x16x32_f16(al, xh[kf], acc, 0, 0, 0);
                acc = __builtin_amdgcn_mfma_f32_16x16x32_f16(ah, xl[kf], acc, 0, 0, 0);
            }
            #pragma unroll
            for (int i = 0; i < 4; ++i) {
                int co = mt*16 + 4*g + i;
                vt[((size_t)b * CC + co) * NN + n0 + cl] = (_Float16)acc[i];
            }
        }
    }
}

// ------------------------------------------------------------------
// Flash attention, split-K x4 -- round-8 design (resubmitted after
// infra failure): barrier-free, LDS-free. Each 64-thread block is ONE
// independent wave handling 32 q-rows x 1024 keys. At CC=64 the 32x32
// A-fragments are per-lane CONTIGUOUS 16B global reads (K: row
// kc*64+q32; V^T: row c_out=q32), so K/V come straight from L2
// (~2 MB/batch, XCD-resident via blk&7=batch) -- no staging, no
// double-buffer, no __syncthreads in the loop. Round-7 showed
// occupancy was the bottleneck (18.7%: s/o accumulators are 64 AGPRs
// on top of 108 VGPRs -> 2 waves/SIMD); free-running waves overlap
// instead. Softmax machinery (LUT mask expand, packed-fp16 masked
// max, clamp-0 stabilizer, defer-max THR=8, post-exp AND, shfl_xor
// redistribute, normalized po epilogue) unchanged from round 7.
// ------------------------------------------------------------------
__global__ __launch_bounds__(64) void gat_attn(
    const _Float16* __restrict__ qg,
    const _Float16* __restrict__ kf16, const _Float16* __restrict__ vtb,
    const unsigned long long* __restrict__ M,
    _Float16* __restrict__ po, float2* __restrict__ pml)
{
    __shared__ alignas(8) uint2 LUT[16];              // nib -> 2 halfword AND-masks
    const int lane = threadIdx.x;
    const int q32 = lane & 31, hi = lane >> 5;
    const int blk = blockIdx.x;        // 4096
    const int b  = blk & 7;            // batch == XCD
    const int sp = (blk >> 3) & 3;     // key split
    const int Q0 = (blk >> 5) * 32;    // q-row base (128 wave-tiles)
    const int c0 = sp * 16;            // first 64-key chunk of this split

    if (lane < 16) {
        unsigned n = lane;
        LUT[n] = make_uint2(((n & 1u) ? 0x0000FFFFu : 0u) | ((n & 2u) ? 0xFFFF0000u : 0u),
                            ((n & 4u) ? 0x0000FFFFu : 0u) | ((n & 8u) ? 0xFFFF0000u : 0u));
    }
    __syncthreads();

    half8 qf[4];                                       // B-frag: c = kf*16 + hi*8 + j
    {
        const _Float16* qr = qg + ((size_t)b * NN + Q0 + q32) * CC + hi * 8;
        #pragma unroll
        for (int kf = 0; kf < 4; ++kf) qf[kf] = *(const half8*)(qr + kf * 16);
    }
    // per-lane K/V base pointers (contiguous 16B fragment reads)
    const _Float16* kp = kf16 + ((size_t)b * NN + (size_t)c0 * 64 + q32) * CC + hi * 8;
    const _Float16* vp = vtb + ((size_t)b * CC + q32) * NN + c0 * 64 + hi * 8;
    const unsigned long long* Mrow = M + (size_t)(Q0 + q32) * 64 + c0;

    f32x16 o0 = {}, o1 = {};
    float m_run = 0.f, l_run = 0.f;

    auto pkmax = [](unsigned a, unsigned b) {
        unsigned d;
        asm("v_pk_max_f16 %0, %1, %2" : "=v"(d) : "v"(a), "v"(b));
        return d;
    };

    unsigned long long cm = Mrow[0];
    for (int kc = 0; kc < 16; ++kc) {
        unsigned long long cmn = 0;
        if (kc < 15) cmn = Mrow[kc + 1];   // issue early, consume next iter

        // ---- QK: S^T[key][qrow]; A-frags straight from global (L2)
        const _Float16* kr = kp + (size_t)kc * 64 * CC;
        __builtin_amdgcn_s_setprio(1);
        f32x16 s0 = {}, s1 = {};
        #pragma unroll
        for (int kf = 0; kf < 4; ++kf) {
            half8 ka0 = *(const half8*)(kr + kf * 16);
            half8 ka1 = *(const half8*)(kr + 32 * CC + kf * 16);
            s0 = __builtin_amdgcn_mfma_f32_32x32x16_f16(ka0, qf[kf], s0, 0, 0, 0);
            s1 = __builtin_amdgcn_mfma_f32_32x32x16_f16(ka1, qf[kf], s1, 0, 0, 0);
        }
        __builtin_amdgcn_s_setprio(0);

        // ---- halfword AND masks via LDS LUT
        const unsigned wlo = (unsigned)cm, whi = (unsigned)(cm >> 32);
        unsigned hm[16];
        #pragma unroll
        for (int kt = 0; kt < 2; ++kt) {
            unsigned w = kt ? whi : wlo;
            #pragma unroll
            for (int a = 0; a < 4; ++a) {
                unsigned nib = (w >> (8 * a + 4 * hi)) & 15u;
                uint2 e = LUT[nib];
                hm[kt*8 + 2*a]     = e.x;
                hm[kt*8 + 2*a + 1] = e.y;
            }
        }
        // ---- masked raw-score max (packed fp16), clamp 0
        {
            unsigned sm[16];
            #pragma unroll
            for (int j = 0; j < 8; ++j) {
                sm[j]   = pk_rtz(s0[2*j], s0[2*j+1]) & hm[j];
                sm[8+j] = pk_rtz(s1[2*j], s1[2*j+1]) & hm[8+j];
            }
            unsigned u0 = pkmax(pkmax(pkmax(sm[0],sm[1]),  pkmax(sm[2],sm[3])),
                                pkmax(pkmax(sm[4],sm[5]),  pkmax(sm[6],sm[7])));
            unsigned u1 = pkmax(pkmax(pkmax(sm[8],sm[9]),  pkmax(sm[10],sm[11])),
                                pkmax(pkmax(sm[12],sm[13]),pkmax(sm[14],sm[15])));
            union { unsigned u; fp16x2 h; } tu; tu.u = pkmax(u0, u1);
            float mx = fmaxf(fmaxf((float)tu.h[0], (float)tu.h[1]), 0.f);
            mx = fmaxf(mx, __shfl_xor(mx, 32));        // partner half
            if (__any(mx > m_run + 8.0f)) {            // defer-max THR=8
                float nm = fmaxf(m_run, mx);
                float alpha = __builtin_amdgcn_exp2f(m_run - nm);
                m_run = nm;
                l_run *= alpha;
                #pragma unroll
                for (int i = 0; i < 16; ++i) { o0[i] *= alpha; o1[i] *= alpha; }
            }
        }
        // ---- p = exp2(leaky(s) - m), pack + mask
        unsigned wp[16];
        #pragma unroll
        for (int j = 0; j < 8; ++j) {
            float p0 = __builtin_amdgcn_exp2f(fmaxf(s0[2*j]   - m_run, fmaf(0.01f, s0[2*j],   -m_run)));
            float p1 = __builtin_amdgcn_exp2f(fmaxf(s0[2*j+1] - m_run, fmaf(0.01f, s0[2*j+1], -m_run)));
            float p2 = __builtin_amdgcn_exp2f(fmaxf(s1[2*j]   - m_run, fmaf(0.01f, s1[2*j],   -m_run)));
            float p3 = __builtin_amdgcn_exp2f(fmaxf(s1[2*j+1] - m_run, fmaf(0.01f, s1[2*j+1], -m_run)));
            wp[j]   = pk_rtz(p0, p1) & hm[j];
            wp[8+j] = pk_rtz(p2, p3) & hm[8+j];
        }
        // ---- l sum over own half (packed); pair-sum in epilogue
        {
            union { unsigned u; fp16x2 h; } z; z.u = 0u;
            fp16x2 acc = z.h;
            #pragma unroll
            for (int j4 = 0; j4 < 4; ++j4) {
                union { unsigned u; fp16x2 h; } x0, x1, x2, x3;
                x0.u = wp[4*j4]; x1.u = wp[4*j4+1]; x2.u = wp[4*j4+2]; x3.u = wp[4*j4+3];
                acc += (x0.h + x1.h) + (x2.h + x3.h);
            }
            l_run += (float)acc[0] + (float)acc[1];
        }
        // ---- redistribute P -> B-frag layout via shfl_xor(32)
        #pragma unroll
        for (int g4 = 0; g4 < 4; ++g4) {
            unsigned w0 = wp[4*g4+0], w1 = wp[4*g4+1];
            unsigned w2 = wp[4*g4+2], w3 = wp[4*g4+3];
            unsigned u = hi ? w0 : w2;
            unsigned v = hi ? w1 : w3;
            unsigned su = (unsigned)__shfl_xor((int)u, 32);
            unsigned sv = (unsigned)__shfl_xor((int)v, 32);
            wp[4*g4+0] = hi ? su : w0;
            wp[4*g4+1] = hi ? sv : w1;
            wp[4*g4+2] = hi ? w2 : su;
            wp[4*g4+3] = hi ? w3 : sv;
        }
        // ---- PV: O^T += V^T * P^T; V A-frags straight from global (L2)
        const _Float16* vr = vp + kc * 64;
        __builtin_amdgcn_s_setprio(1);
        #pragma unroll
        for (int kc4 = 0; kc4 < 4; ++kc4) {
            union { unsigned u[4]; half8 h; } pb;
            pb.u[0] = wp[4*kc4+0]; pb.u[1] = wp[4*kc4+1];
            pb.u[2] = wp[4*kc4+2]; pb.u[3] = wp[4*kc4+3];
            half8 vf0 = *(const half8*)(vr + kc4 * 16);
            half8 vf1 = *(const half8*)(vr + (size_t)32 * NN + kc4 * 16);
            o0 = __builtin_amdgcn_mfma_f32_32x32x16_f16(vf0, pb.h, o0, 0, 0, 0);
            o1 = __builtin_amdgcn_mfma_f32_32x32x16_f16(vf1, pb.h, o1, 0, 0, 0);
        }
        __builtin_amdgcn_s_setprio(0);
        cm = cmn;
    }

    // epilogue: NORMALIZED fp16 partial o/l + (m, l) for combine
    float lt = l_run + __shfl_xor(l_run, 32);
    float invl = (lt > 0.f) ? 1.0f / lt : 0.f;
    size_t base = (size_t)sp * (BATCH * NN) + (size_t)b * NN + Q0 + q32;
    _Float16* orow = po + base * 64;
    #pragma unroll
    for (int a = 0; a < 4; ++a) {
        {
            uint2 ow = { pk_rtz(o0[4*a] * invl, o0[4*a+1] * invl),
                         pk_rtz(o0[4*a+2] * invl, o0[4*a+3] * invl) };
            *(uint2*)(orow + 8*a + 4*hi) = ow;
        }
        {
            uint2 ow = { pk_rtz(o1[4*a] * invl, o1[4*a+1] * invl),
                         pk_rtz(o1[4*a+2] * invl, o1[4*a+3] * invl) };
            *(uint2*)(orow + 32 + 8*a + 4*hi) = ow;
        }
    }
    if (hi == 0) pml[base] = make_float2(m_run, lt);
}

// ------------------------------------------------------------------
// Combine the 4 split-K partials (po holds NORMALIZED o/l):
// out = sum_s (w_s*l_s)*o_s / sum_s (w_s*l_s). 2048 blocks,
// 4 outputs/thread (512 blocks = 2/CU was latency-starved).
// ------------------------------------------------------------------
__global__ __launch_bounds__(256) void gat_comb(
    const _Float16* __restrict__ po, const float2* __restrict__ pml,
    float* __restrict__ out)
{
    int gid = blockIdx.x * 256 + threadIdx.x;     // 524288 threads
    int row = gid >> 4;                            // b*N + n
    int col = (gid & 15) * 4;
    float2 ml[4];
    float Mx = MASKV;
    #pragma unroll
    for (int s = 0; s < 4; ++s) {
        ml[s] = pml[s * (BATCH * NN) + row];
        Mx = fmaxf(Mx, ml[s].x);
    }
    float w[4], den = 0.f;
    #pragma unroll
    for (int s = 0; s < 4; ++s) {
        w[s] = __builtin_amdgcn_exp2f(ml[s].x - Mx) * ml[s].y;  // w_s * l_s
        den += w[s];
    }
    float inv = 1.0f / den;                        // diag guarantees den > 0
    float acc[4] = {};
    #pragma unroll
    for (int s = 0; s < 4; ++s) {
        const _Float16* p = po + ((size_t)s * (BATCH * NN) + row) * 64 + col;
        float a = w[s] * inv;
        half4 v = *(const half4*)(p);
        #pragma unroll
        for (int j = 0; j < 4; ++j) acc[j] += a * (float)v[j];
    }
    f32x4 r = {acc[0], acc[1], acc[2], acc[3]};
    *(f32x4*)(out + (size_t)row * 64 + col) = r;
}

extern "C" void kernel_launch(void* const* d_in, const int* in_sizes, int n_in,
                              void* d_out, int out_size, void* d_ws, size_t ws_size,
                              hipStream_t stream) {
    const float* X  = (const float*)d_in[0];
    const int*   A  = (const int*)d_in[1];
    const float* W0 = (const float*)d_in[2];
    const float* Wq = (const float*)d_in[3];
    const float* Wk = (const float*)d_in[4];
    float* out = (float*)d_out;
    char* ws = (char*)d_ws;
    const size_t SZ = (size_t)BATCH * NN * CC * 2;        // 4 MB per fp16 tensor
    _Float16* qh  = (_Float16*)(ws);
    _Float16* kbf = (_Float16*)(ws + SZ);
    _Float16* vtb = (_Float16*)(ws + 2*SZ);
    char* Mbase = ws + 3*SZ;                               // 2 MB mask
    _Float16* po = (_Float16*)(Mbase + 2*1024*1024);       // 16 MB
    float2* pml  = (float2*)(Mbase + 2*1024*1024 + 4*SZ);  // 1 MB

    hipLaunchKernelGGL(gat_prep, dim3(4608), dim3(256), 0, stream,
                       X, W0, Wq, Wk, A, qh, kbf, vtb, (unsigned short*)Mbase);
    hipLaunchKernelGGL(gat_attn, dim3(4096), dim3(64), 0, stream, qh, kbf, vtb,
                       (const unsigned long long*)Mbase, po, pml);
    hipLaunchKernelGGL(gat_comb, dim3(2048), dim3(256), 0, stream, po, pml, out);
}

// Round 10
// 194.417 us; speedup vs baseline: 1.2756x; 1.2756x over previous
//
#include <hip/hip_runtime.h>
#include <stdint.h>

#define BATCH 8
#define NN 4096
#define CC 64
#define MASKV -1.0e30f
#define LOG2E 1.4426950408889634f

typedef _Float16 half8 __attribute__((ext_vector_type(8)));
typedef _Float16 half4 __attribute__((ext_vector_type(4)));
typedef __fp16 fp16x2 __attribute__((ext_vector_type(2)));
typedef float f32x4 __attribute__((ext_vector_type(4)));
typedef float f32x16 __attribute__((ext_vector_type(16)));

typedef __attribute__((address_space(1))) const unsigned int gu32;
typedef __attribute__((address_space(3))) unsigned int lu32;
#define GLL16(gp, lp) __builtin_amdgcn_global_load_lds( \
    (gu32*)(uintptr_t)(gp), (lu32*)(unsigned)(uintptr_t)(lp), 16, 0, 0)

__device__ __forceinline__ unsigned pk_rtz(float a, float b) {
    union { fp16x2 h; unsigned u; } r;
    r.h = __builtin_amdgcn_cvt_pkrtz(a, b);
    return r.u;
}

// ------------------------------------------------------------------
// Fused prep: blocks 0-511 = projection (q fp16 pre-scaled by log2e,
// k fp16, vT fp16 [b][c][n]; split-compensated fp16 MFMA); blocks
// 512-4607 = adjacency bitmask (forced diagonal, compact 2 MB).
// ------------------------------------------------------------------
__global__ __launch_bounds__(256) void gat_prep(
    const float* __restrict__ X, const float* __restrict__ W0,
    const float* __restrict__ Wq, const float* __restrict__ Wk,
    const int* __restrict__ A,
    _Float16* __restrict__ qh, _Float16* __restrict__ kb,
    _Float16* __restrict__ vt, unsigned short* __restrict__ M16)
{
    __shared__ alignas(16) _Float16 WTh[3][64][72];
    __shared__ alignas(16) _Float16 WTl[3][64][72];
    const int t = threadIdx.x;
    if (blockIdx.x >= 512) {                       // ---- mask part
        const int row = blockIdx.x - 512;
        const int4* ap = (const int4*)(A + (size_t)row * NN + t * 16);
        unsigned m = 0;
        #pragma unroll
        for (int j = 0; j < 4; ++j) {
            int4 a = ap[j];
            m |= (a.x != 0 ? 1u : 0u) << (4*j);
            m |= (a.y != 0 ? 1u : 0u) << (4*j + 1);
            m |= (a.z != 0 ? 1u : 0u) << (4*j + 2);
            m |= (a.w != 0 ? 1u : 0u) << (4*j + 3);
        }
        if (t == (row >> 4)) m |= 1u << (row & 15);
        M16[(size_t)row * 256 + t] = (unsigned short)m;
        return;
    }
    // ---- projection part
    const float* Ws[3] = {W0, Wq, Wk};
    for (int e = t; e < 4096; e += 256) {
        int k = e >> 6, c = e & 63;
        #pragma unroll
        for (int m = 0; m < 3; ++m) {
            float w = Ws[m][e];
            _Float16 hi = (_Float16)w;
            WTh[m][c][k] = hi;
            WTl[m][c][k] = (_Float16)(w - (float)hi);
        }
    }
    __syncthreads();
    const int lane = t & 63, wv = t >> 6;
    const int cl = lane & 15, g = lane >> 4;
    int tile = blockIdx.x * 4 + wv;
    int gr = tile * 16;
    const float* xr = X + (size_t)(gr + cl) * CC;
    half8 xh[2], xl[2];
    #pragma unroll
    for (int kf = 0; kf < 2; ++kf) {
        f32x4 a0 = *(const f32x4*)(xr + g*8 + kf*32);
        f32x4 a1 = *(const f32x4*)(xr + g*8 + kf*32 + 4);
        half8 h, l;
        #pragma unroll
        for (int j = 0; j < 4; ++j) {
            _Float16 h0 = (_Float16)a0[j], h1 = (_Float16)a1[j];
            h[j]   = h0; l[j]   = (_Float16)(a0[j] - (float)h0);
            h[j+4] = h1; l[j+4] = (_Float16)(a1[j] - (float)h1);
        }
        xh[kf] = h; xl[kf] = l;
    }
    #pragma unroll
    for (int mat = 1; mat <= 2; ++mat) {
        #pragma unroll
        for (int nt = 0; nt < 4; ++nt) {
            f32x4 acc = {0.f, 0.f, 0.f, 0.f};
            #pragma unroll
            for (int kf = 0; kf < 2; ++kf) {
                half8 bh = *(const half8*)&WTh[mat][nt*16 + cl][g*8 + kf*32];
                half8 bl = *(const half8*)&WTl[mat][nt*16 + cl][g*8 + kf*32];
                acc = __builtin_amdgcn_mfma_f32_16x16x32_f16(xh[kf], bh, acc, 0, 0, 0);
                acc = __builtin_amdgcn_mfma_f32_16x16x32_f16(xl[kf], bh, acc, 0, 0, 0);
                acc = __builtin_amdgcn_mfma_f32_16x16x32_f16(xh[kf], bl, acc, 0, 0, 0);
            }
            #pragma unroll
            for (int i = 0; i < 4; ++i) {
                size_t off = (size_t)(gr + 4*g + i) * CC + nt*16 + cl;
                if (mat == 1) qh[off] = (_Float16)(acc[i] * LOG2E);
                else          kb[off] = (_Float16)acc[i];
            }
        }
    }
    {
        int b = gr >> 12, n0 = gr & (NN - 1);
        #pragma unroll
        for (int mt = 0; mt < 4; ++mt) {
            f32x4 acc = {0.f, 0.f, 0.f, 0.f};
            #pragma unroll
            for (int kf = 0; kf < 2; ++kf) {
                half8 ah = *(const half8*)&WTh[0][mt*16 + cl][g*8 + kf*32];
                half8 al = *(const half8*)&WTl[0][mt*16 + cl][g*8 + kf*32];
                acc = __builtin_amdgcn_mfma_f32_16x16x32_f16(ah, xh[kf], acc, 0, 0, 0);
                acc = __builtin_amdgcn_mfma_f32_16x16x32_f16(al, xh[kf], acc, 0, 0, 0);
                acc = __builtin_amdgcn_mfma_f32_16x16x32_f16(ah, xl[kf], acc, 0, 0, 0);
            }
            #pragma unroll
            for (int i = 0; i < 4; ++i) {
                int co = mt*16 + 4*g + i;
                vt[((size_t)b * CC + co) * NN + n0 + cl] = (_Float16)acc[i];
            }
        }
    }
}

// ------------------------------------------------------------------
// Flash attention, split-K x4 -- round-10: r7 structure (GLL staging,
// XOR-swizzle, 1 barrier/iter; 86us verified) + cross-iteration QK
// pipelining on TRIPLE-buffered LDS: stage tile kc+2 async, compute
// QK(kc+1) into s_next at the TOP of iter kc (K(kc+1) resident since
// the previous barrier). QK(kc+1)'s 8 MFMAs have no consumer until
// next iter -> they run entirely under softmax(kc)'s serial VALU
// chain on the matrix pipe. Uses the free headroom of the 256-reg
// allocation band (+32 regs s_next); occupancy unchanged, ILP ~2x.
// r9 lesson: global-direct fragments regressed (L2 latency entered
// the MFMA chain, occupancy did NOT rise) -- keep LDS staging.
// ------------------------------------------------------------------
__global__ __launch_bounds__(256) void gat_attn(
    const _Float16* __restrict__ qg,
    const _Float16* __restrict__ kf16, const _Float16* __restrict__ vtb,
    const unsigned long long* __restrict__ M,
    _Float16* __restrict__ po, float2* __restrict__ pml)
{
    __shared__ alignas(16) _Float16 Kt[3][64][64];    // [buf][key][c_in], swizzled
    __shared__ alignas(16) _Float16 Vt[3][64][64];    // [buf][c_out][key], swizzled
    __shared__ alignas(8) uint2 LUT[16];              // nib -> 2 halfword AND-masks
    const int t = threadIdx.x;
    const int lane = t & 63, wv = t >> 6;
    const int q32 = lane & 31, hi = lane >> 5;
    const int blk = blockIdx.x;        // 1024
    const int b  = blk & 7;            // batch == XCD
    const int sp = (blk >> 3) & 3;     // key split
    const int qb = blk >> 5;           // q tile 0..31
    const int Q0 = qb * 128 + wv * 32;
    const int c0 = sp * 16;
    const int swz = (q32 & 7) << 4;    // read-side XOR (row%8)

    if (t < 16) {
        unsigned n = t;
        LUT[n] = make_uint2(((n & 1u) ? 0x0000FFFFu : 0u) | ((n & 2u) ? 0xFFFF0000u : 0u),
                            ((n & 4u) ? 0x0000FFFFu : 0u) | ((n & 8u) ? 0xFFFF0000u : 0u));
    }

    // ---- async staging setup (wave wv owns one 4KB region)
    const int lrow = lane >> 3;                          // 0..7
    const int lcol = ((lane & 7) * 16) ^ (lrow << 4);    // pre-swizzled byte col
    const bool isK = (wv < 2);
    const int seg = isK ? wv : (wv - 2);
    const char* gsrc0 = isK
        ? (const char*)(kf16 + (size_t)b * NN * CC)
            + (size_t)c0 * 8192 + (size_t)seg * 4096 + lrow * 128 + lcol
        : (const char*)(vtb + (size_t)b * CC * NN)
            + (size_t)c0 * 128 + ((size_t)(seg * 32 + lrow)) * 8192 + lcol;
    const int istride = isK ? 1024 : 65536;
    const int cstride = isK ? 8192 : 128;

    auto stage = [&](int rel, int bufi) {
        const char* s = gsrc0 + (size_t)rel * cstride;
        char* d = isK ? ((char*)&Kt[bufi][0][0] + seg * 4096)
                      : ((char*)&Vt[bufi][0][0] + seg * 4096);
        #pragma unroll
        for (int i = 0; i < 4; ++i)
            GLL16(s + i * istride, d + i * 1024);
    };
    auto pkmax = [](unsigned a, unsigned b) {
        unsigned d;
        asm("v_pk_max_f16 %0, %1, %2" : "=v"(d) : "v"(a), "v"(b));
        return d;
    };

    half8 qf[4];                                       // B-frag: c = kf*16 + hi*8 + j
    {
        const _Float16* qr = qg + ((size_t)b * NN + Q0 + q32) * CC + hi * 8;
        #pragma unroll
        for (int kf = 0; kf < 4; ++kf) qf[kf] = *(const half8*)(qr + kf * 16);
    }
    const unsigned long long* Mrow = M + (size_t)(Q0 + q32) * 64 + c0;

    auto do_qk = [&](int bufi, f32x16& s0, f32x16& s1) {
        const char* kbase = (const char*)&Kt[bufi][0][0] + q32 * 128;
        __builtin_amdgcn_s_setprio(1);
        #pragma unroll
        for (int kf = 0; kf < 4; ++kf) {
            const int col = (kf * 32 + hi * 16) ^ swz;
            half8 ka0 = *(const half8*)(kbase + col);
            half8 ka1 = *(const half8*)(kbase + 4096 + col);
            s0 = __builtin_amdgcn_mfma_f32_32x32x16_f16(ka0, qf[kf], s0, 0, 0, 0);
            s1 = __builtin_amdgcn_mfma_f32_32x32x16_f16(ka1, qf[kf], s1, 0, 0, 0);
        }
        __builtin_amdgcn_s_setprio(0);
    };

    f32x16 o0 = {}, o1 = {};
    float m_run = 0.f, l_run = 0.f;

    // prologue: stage tiles 0,1; QK(0)
    stage(0, 0);
    stage(1, 1);
    unsigned long long cm0 = Mrow[0], cm1 = Mrow[1], cm2 = 0;
    __syncthreads();                      // drains both stages (+LUT ready)

    f32x16 sc0 = {}, sc1 = {};
    do_qk(0, sc0, sc1);

    for (int kc = 0; kc < 16; ++kc) {
        // ---- stage kc+2 (async) + mask prefetch
        if (kc < 14) { stage(kc + 2, (kc + 2) % 3); cm2 = Mrow[kc + 2]; }
        // ---- QK for NEXT tile (no consumer this iter: pure overlap)
        f32x16 sn0 = {}, sn1 = {};
        if (kc < 15) do_qk((kc + 1) % 3, sn0, sn1);

        // ---- halfword AND masks via LDS LUT
        const unsigned wlo = (unsigned)cm0, whi = (unsigned)(cm0 >> 32);
        unsigned hm[16];
        #pragma unroll
        for (int kt = 0; kt < 2; ++kt) {
            unsigned w = kt ? whi : wlo;
            #pragma unroll
            for (int a = 0; a < 4; ++a) {
                unsigned nib = (w >> (8 * a + 4 * hi)) & 15u;
                uint2 e = LUT[nib];
                hm[kt*8 + 2*a]     = e.x;
                hm[kt*8 + 2*a + 1] = e.y;
            }
        }
        // ---- masked raw-score max (packed fp16), clamp 0
        {
            unsigned sm[16];
            #pragma unroll
            for (int j = 0; j < 8; ++j) {
                sm[j]   = pk_rtz(sc0[2*j], sc0[2*j+1]) & hm[j];
                sm[8+j] = pk_rtz(sc1[2*j], sc1[2*j+1]) & hm[8+j];
            }
            unsigned u0 = pkmax(pkmax(pkmax(sm[0],sm[1]),  pkmax(sm[2],sm[3])),
                                pkmax(pkmax(sm[4],sm[5]),  pkmax(sm[6],sm[7])));
            unsigned u1 = pkmax(pkmax(pkmax(sm[8],sm[9]),  pkmax(sm[10],sm[11])),
                                pkmax(pkmax(sm[12],sm[13]),pkmax(sm[14],sm[15])));
            union { unsigned u; fp16x2 h; } tu; tu.u = pkmax(u0, u1);
            float mx = fmaxf(fmaxf((float)tu.h[0], (float)tu.h[1]), 0.f);
            mx = fmaxf(mx, __shfl_xor(mx, 32));        // partner half
            if (__any(mx > m_run + 8.0f)) {            // defer-max THR=8
                float nm = fmaxf(m_run, mx);
                float alpha = __builtin_amdgcn_exp2f(m_run - nm);
                m_run = nm;
                l_run *= alpha;
                #pragma unroll
                for (int i = 0; i < 16; ++i) { o0[i] *= alpha; o1[i] *= alpha; }
            }
        }
        // ---- p = exp2(leaky(s) - m), pack + mask
        unsigned wp[16];
        #pragma unroll
        for (int j = 0; j < 8; ++j) {
            float p0 = __builtin_amdgcn_exp2f(fmaxf(sc0[2*j]   - m_run, fmaf(0.01f, sc0[2*j],   -m_run)));
            float p1 = __builtin_amdgcn_exp2f(fmaxf(sc0[2*j+1] - m_run, fmaf(0.01f, sc0[2*j+1], -m_run)));
            float p2 = __builtin_amdgcn_exp2f(fmaxf(sc1[2*j]   - m_run, fmaf(0.01f, sc1[2*j],   -m_run)));
            float p3 = __builtin_amdgcn_exp2f(fmaxf(sc1[2*j+1] - m_run, fmaf(0.01f, sc1[2*j+1], -m_run)));
            wp[j]   = pk_rtz(p0, p1) & hm[j];
            wp[8+j] = pk_rtz(p2, p3) & hm[8+j];
        }
        // ---- l sum over own half (packed); pair-sum in epilogue
        {
            union { unsigned u; fp16x2 h; } z; z.u = 0u;
            fp16x2 acc = z.h;
            #pragma unroll
            for (int j4 = 0; j4 < 4; ++j4) {
                union { unsigned u; fp16x2 h; } x0, x1, x2, x3;
                x0.u = wp[4*j4]; x1.u = wp[4*j4+1]; x2.u = wp[4*j4+2]; x3.u = wp[4*j4+3];
                acc += (x0.h + x1.h) + (x2.h + x3.h);
            }
            l_run += (float)acc[0] + (float)acc[1];
        }
        // ---- redistribute P -> B-frag layout via shfl_xor(32)
        #pragma unroll
        for (int g4 = 0; g4 < 4; ++g4) {
            unsigned w0 = wp[4*g4+0], w1 = wp[4*g4+1];
            unsigned w2 = wp[4*g4+2], w3 = wp[4*g4+3];
            unsigned u = hi ? w0 : w2;
            unsigned v = hi ? w1 : w3;
            unsigned su = (unsigned)__shfl_xor((int)u, 32);
            unsigned sv = (unsigned)__shfl_xor((int)v, 32);
            wp[4*g4+0] = hi ? su : w0;
            wp[4*g4+1] = hi ? sv : w1;
            wp[4*g4+2] = hi ? w2 : su;
            wp[4*g4+3] = hi ? w3 : sv;
        }
        // ---- PV: O^T += V^T * P^T
        const char* vb = (const char*)&Vt[kc % 3][0][0] + q32 * 128;
        __builtin_amdgcn_s_setprio(1);
        #pragma unroll
        for (int kc4 = 0; kc4 < 4; ++kc4) {
            union { unsigned u[4]; half8 h; } pb;
            pb.u[0] = wp[4*kc4+0]; pb.u[1] = wp[4*kc4+1];
            pb.u[2] = wp[4*kc4+2]; pb.u[3] = wp[4*kc4+3];
            const int col = (kc4 * 32 + hi * 16) ^ swz;
            half8 vf0 = *(const half8*)(vb + col);
            half8 vf1 = *(const half8*)(vb + 4096 + col);
            o0 = __builtin_amdgcn_mfma_f32_32x32x16_f16(vf0, pb.h, o0, 0, 0, 0);
            o1 = __builtin_amdgcn_mfma_f32_32x32x16_f16(vf1, pb.h, o1, 0, 0, 0);
        }
        __builtin_amdgcn_s_setprio(0);
        // ---- rotate pipeline state
        cm0 = cm1; cm1 = cm2;
        sc0 = sn0; sc1 = sn1;
        if (kc < 15) __syncthreads();     // drains stage(kc+2); buf rotation safe
    }

    // epilogue: NORMALIZED fp16 partial o/l + (m, l) for combine
    float lt = l_run + __shfl_xor(l_run, 32);
    float invl = (lt > 0.f) ? 1.0f / lt : 0.f;
    size_t base = (size_t)sp * (BATCH * NN) + (size_t)b * NN + Q0 + q32;
    _Float16* orow = po + base * 64;
    #pragma unroll
    for (int a = 0; a < 4; ++a) {
        {
            uint2 ow = { pk_rtz(o0[4*a] * invl, o0[4*a+1] * invl),
                         pk_rtz(o0[4*a+2] * invl, o0[4*a+3] * invl) };
            *(uint2*)(orow + 8*a + 4*hi) = ow;
        }
        {
            uint2 ow = { pk_rtz(o1[4*a] * invl, o1[4*a+1] * invl),
                         pk_rtz(o1[4*a+2] * invl, o1[4*a+3] * invl) };
            *(uint2*)(orow + 32 + 8*a + 4*hi) = ow;
        }
    }
    if (hi == 0) pml[base] = make_float2(m_run, lt);
}

// ------------------------------------------------------------------
// Combine the 4 split-K partials (po holds NORMALIZED o/l):
// out = sum_s (w_s*l_s)*o_s / sum_s (w_s*l_s). 2048 blocks.
// ------------------------------------------------------------------
__global__ __launch_bounds__(256) void gat_comb(
    const _Float16* __restrict__ po, const float2* __restrict__ pml,
    float* __restrict__ out)
{
    int gid = blockIdx.x * 256 + threadIdx.x;     // 524288 threads
    int row = gid >> 4;                            // b*N + n
    int col = (gid & 15) * 4;
    float2 ml[4];
    float Mx = MASKV;
    #pragma unroll
    for (int s = 0; s < 4; ++s) {
        ml[s] = pml[s * (BATCH * NN) + row];
        Mx = fmaxf(Mx, ml[s].x);
    }
    float w[4], den = 0.f;
    #pragma unroll
    for (int s = 0; s < 4; ++s) {
        w[s] = __builtin_amdgcn_exp2f(ml[s].x - Mx) * ml[s].y;  // w_s * l_s
        den += w[s];
    }
    float inv = 1.0f / den;                        // diag guarantees den > 0
    float acc[4] = {};
    #pragma unroll
    for (int s = 0; s < 4; ++s) {
        const _Float16* p = po + ((size_t)s * (BATCH * NN) + row) * 64 + col;
        float a = w[s] * inv;
        half4 v = *(const half4*)(p);
        #pragma unroll
        for (int j = 0; j < 4; ++j) acc[j] += a * (float)v[j];
    }
    f32x4 r = {acc[0], acc[1], acc[2], acc[3]};
    *(f32x4*)(out + (size_t)row * 64 + col) = r;
}

extern "C" void kernel_launch(void* const* d_in, const int* in_sizes, int n_in,
                              void* d_out, int out_size, void* d_ws, size_t ws_size,
                              hipStream_t stream) {
    const float* X  = (const float*)d_in[0];
    const int*   A  = (const int*)d_in[1];
    const float* W0 = (const float*)d_in[2];
    const float* Wq = (const float*)d_in[3];
    const float* Wk = (const float*)d_in[4];
    float* out = (float*)d_out;
    char* ws = (char*)d_ws;
    const size_t SZ = (size_t)BATCH * NN * CC * 2;        // 4 MB per fp16 tensor
    _Float16* qh  = (_Float16*)(ws);
    _Float16* kbf = (_Float16*)(ws + SZ);
    _Float16* vtb = (_Float16*)(ws + 2*SZ);
    char* Mbase = ws + 3*SZ;                               // 2 MB mask
    _Float16* po = (_Float16*)(Mbase + 2*1024*1024);       // 16 MB
    float2* pml  = (float2*)(Mbase + 2*1024*1024 + 4*SZ);  // 1 MB

    hipLaunchKernelGGL(gat_prep, dim3(4608), dim3(256), 0, stream,
                       X, W0, Wq, Wk, A, qh, kbf, vtb, (unsigned short*)Mbase);
    hipLaunchKernelGGL(gat_attn, dim3(1024), dim3(256), 0, stream, qh, kbf, vtb,
                       (const unsigned long long*)Mbase, po, pml);
    hipLaunchKernelGGL(gat_comb, dim3(2048), dim3(256), 0, stream, po, pml, out);
}

// Round 11
// 187.894 us; speedup vs baseline: 1.3199x; 1.0347x over previous
//
#include <hip/hip_runtime.h>
#include <stdint.h>

#define BATCH 8
#define NN 4096
#define CC 64
#define MASKV -1.0e30f
#define LOG2E 1.4426950408889634f

typedef _Float16 half8 __attribute__((ext_vector_type(8)));
typedef _Float16 half4 __attribute__((ext_vector_type(4)));
typedef __fp16 fp16x2 __attribute__((ext_vector_type(2)));
typedef float f32x4 __attribute__((ext_vector_type(4)));
typedef float f32x16 __attribute__((ext_vector_type(16)));

typedef __attribute__((address_space(1))) const unsigned int gu32;
typedef __attribute__((address_space(3))) unsigned int lu32;
#define GLL16(gp, lp) __builtin_amdgcn_global_load_lds( \
    (gu32*)(uintptr_t)(gp), (lu32*)(unsigned)(uintptr_t)(lp), 16, 0, 0)

__device__ __forceinline__ unsigned pk_rtz(float a, float b) {
    union { fp16x2 h; unsigned u; } r;
    r.h = __builtin_amdgcn_cvt_pkrtz(a, b);
    return r.u;
}

// ------------------------------------------------------------------
// Fused prep: blocks 0-511 = projection (q fp16 pre-scaled by log2e,
// k fp16, vT fp16 [b][c][n]; split-compensated fp16 MFMA); blocks
// 512-4607 = adjacency bitmask (forced diagonal, compact 2 MB).
// ------------------------------------------------------------------
__global__ __launch_bounds__(256) void gat_prep(
    const float* __restrict__ X, const float* __restrict__ W0,
    const float* __restrict__ Wq, const float* __restrict__ Wk,
    const int* __restrict__ A,
    _Float16* __restrict__ qh, _Float16* __restrict__ kb,
    _Float16* __restrict__ vt, unsigned short* __restrict__ M16)
{
    __shared__ alignas(16) _Float16 WTh[3][64][72];
    __shared__ alignas(16) _Float16 WTl[3][64][72];
    const int t = threadIdx.x;
    if (blockIdx.x >= 512) {                       // ---- mask part
        const int row = blockIdx.x - 512;
        const int4* ap = (const int4*)(A + (size_t)row * NN + t * 16);
        unsigned m = 0;
        #pragma unroll
        for (int j = 0; j < 4; ++j) {
            int4 a = ap[j];
            m |= (a.x != 0 ? 1u : 0u) << (4*j);
            m |= (a.y != 0 ? 1u : 0u) << (4*j + 1);
            m |= (a.z != 0 ? 1u : 0u) << (4*j + 2);
            m |= (a.w != 0 ? 1u : 0u) << (4*j + 3);
        }
        if (t == (row >> 4)) m |= 1u << (row & 15);
        M16[(size_t)row * 256 + t] = (unsigned short)m;
        return;
    }
    // ---- projection part
    const float* Ws[3] = {W0, Wq, Wk};
    for (int e = t; e < 4096; e += 256) {
        int k = e >> 6, c = e & 63;
        #pragma unroll
        for (int m = 0; m < 3; ++m) {
            float w = Ws[m][e];
            _Float16 hi = (_Float16)w;
            WTh[m][c][k] = hi;
            WTl[m][c][k] = (_Float16)(w - (float)hi);
        }
    }
    __syncthreads();
    const int lane = t & 63, wv = t >> 6;
    const int cl = lane & 15, g = lane >> 4;
    int tile = blockIdx.x * 4 + wv;
    int gr = tile * 16;
    const float* xr = X + (size_t)(gr + cl) * CC;
    half8 xh[2], xl[2];
    #pragma unroll
    for (int kf = 0; kf < 2; ++kf) {
        f32x4 a0 = *(const f32x4*)(xr + g*8 + kf*32);
        f32x4 a1 = *(const f32x4*)(xr + g*8 + kf*32 + 4);
        half8 h, l;
        #pragma unroll
        for (int j = 0; j < 4; ++j) {
            _Float16 h0 = (_Float16)a0[j], h1 = (_Float16)a1[j];
            h[j]   = h0; l[j]   = (_Float16)(a0[j] - (float)h0);
            h[j+4] = h1; l[j+4] = (_Float16)(a1[j] - (float)h1);
        }
        xh[kf] = h; xl[kf] = l;
    }
    #pragma unroll
    for (int mat = 1; mat <= 2; ++mat) {
        #pragma unroll
        for (int nt = 0; nt < 4; ++nt) {
            f32x4 acc = {0.f, 0.f, 0.f, 0.f};
            #pragma unroll
            for (int kf = 0; kf < 2; ++kf) {
                half8 bh = *(const half8*)&WTh[mat][nt*16 + cl][g*8 + kf*32];
                half8 bl = *(const half8*)&WTl[mat][nt*16 + cl][g*8 + kf*32];
                acc = __builtin_amdgcn_mfma_f32_16x16x32_f16(xh[kf], bh, acc, 0, 0, 0);
                acc = __builtin_amdgcn_mfma_f32_16x16x32_f16(xl[kf], bh, acc, 0, 0, 0);
                acc = __builtin_amdgcn_mfma_f32_16x16x32_f16(xh[kf], bl, acc, 0, 0, 0);
            }
            #pragma unroll
            for (int i = 0; i < 4; ++i) {
                size_t off = (size_t)(gr + 4*g + i) * CC + nt*16 + cl;
                if (mat == 1) qh[off] = (_Float16)(acc[i] * LOG2E);
                else          kb[off] = (_Float16)acc[i];
            }
        }
    }
    {
        int b = gr >> 12, n0 = gr & (NN - 1);
        #pragma unroll
        for (int mt = 0; mt < 4; ++mt) {
            f32x4 acc = {0.f, 0.f, 0.f, 0.f};
            #pragma unroll
            for (int kf = 0; kf < 2; ++kf) {
                half8 ah = *(const half8*)&WTh[0][mt*16 + cl][g*8 + kf*32];
                half8 al = *(const half8*)&WTl[0][mt*16 + cl][g*8 + kf*32];
                acc = __builtin_amdgcn_mfma_f32_16x16x32_f16(ah, xh[kf], acc, 0, 0, 0);
                acc = __builtin_amdgcn_mfma_f32_16x16x32_f16(al, xh[kf], acc, 0, 0, 0);
                acc = __builtin_amdgcn_mfma_f32_16x16x32_f16(ah, xl[kf], acc, 0, 0, 0);
            }
            #pragma unroll
            for (int i = 0; i < 4; ++i) {
                int co = mt*16 + 4*g + i;
                vt[((size_t)b * CC + co) * NN + n0 + cl] = (_Float16)acc[i];
            }
        }
    }
}

// ------------------------------------------------------------------
// Flash attention, split-K x4 -- round-11: r7 structure (GLL staging,
// XOR-swizzle, double-buffer, 1 barrier/iter; 86us verified) with the
// register footprint squeezed below the 3-waves/SIMD cliff:
//  * unified reg budget is 512/wave-slot; r7 sat at 108 VGPR + 64
//    AGPR = 172 -> 2 waves/SIMD. The 3-wave band needs <= 170.
//  * hm[16] mask array ELIMINATED: halfword masks regenerated per
//    use-site (max chain, exp-pack) from the compact u64 via LUT.
//  * sm[16] max temporary ELIMINATED: two parallel running pkmax
//    chains (masked-to-+0 entries implement the clamp-0 stabilizer).
//  * __launch_bounds__(256, 3) pins the allocator to the 3-wave band.
// r10 lesson: cross-iter QK pipelining neutral (compiler reschedules);
// r9 lesson: global-direct fragments regress. The lever is TLP.
// ------------------------------------------------------------------
__global__ __launch_bounds__(256, 3) void gat_attn(
    const _Float16* __restrict__ qg,
    const _Float16* __restrict__ kf16, const _Float16* __restrict__ vtb,
    const unsigned long long* __restrict__ M,
    _Float16* __restrict__ po, float2* __restrict__ pml)
{
    __shared__ alignas(16) _Float16 Kt[2][64][64];    // [buf][key][c_in], swizzled
    __shared__ alignas(16) _Float16 Vt[2][64][64];    // [buf][c_out][key], swizzled
    __shared__ alignas(8) uint2 LUT[16];              // nib -> 2 halfword AND-masks
    const int t = threadIdx.x;
    const int lane = t & 63, wv = t >> 6;
    const int q32 = lane & 31, hi = lane >> 5;
    const int blk = blockIdx.x;        // 1024
    const int b  = blk & 7;            // batch == XCD
    const int sp = (blk >> 3) & 3;     // key split
    const int qb = blk >> 5;           // q tile 0..31
    const int Q0 = qb * 128 + wv * 32;
    const int c0 = sp * 16;
    const int swz = (q32 & 7) << 4;    // read-side XOR (row%8)

    if (t < 16) {
        unsigned n = t;
        LUT[n] = make_uint2(((n & 1u) ? 0x0000FFFFu : 0u) | ((n & 2u) ? 0xFFFF0000u : 0u),
                            ((n & 4u) ? 0x0000FFFFu : 0u) | ((n & 8u) ? 0xFFFF0000u : 0u));
    }

    // ---- async staging setup (wave wv owns one 4KB region)
    const int lrow = lane >> 3;                          // 0..7
    const int lcol = ((lane & 7) * 16) ^ (lrow << 4);    // pre-swizzled byte col
    const bool isK = (wv < 2);
    const int seg = isK ? wv : (wv - 2);
    const char* gsrc0 = isK
        ? (const char*)(kf16 + (size_t)b * NN * CC)
            + (size_t)c0 * 8192 + (size_t)seg * 4096 + lrow * 128 + lcol
        : (const char*)(vtb + (size_t)b * CC * NN)
            + (size_t)c0 * 128 + ((size_t)(seg * 32 + lrow)) * 8192 + lcol;
    const int istride = isK ? 1024 : 65536;
    const int cstride = isK ? 8192 : 128;

    auto stage = [&](int rel, int bufi) {
        const char* s = gsrc0 + (size_t)rel * cstride;
        char* d = isK ? ((char*)&Kt[bufi][0][0] + seg * 4096)
                      : ((char*)&Vt[bufi][0][0] + seg * 4096);
        #pragma unroll
        for (int i = 0; i < 4; ++i)
            GLL16(s + i * istride, d + i * 1024);
    };
    auto pkmax = [](unsigned a, unsigned b) {
        unsigned d;
        asm("v_pk_max_f16 %0, %1, %2" : "=v"(d) : "v"(a), "v"(b));
        return d;
    };

    half8 qf[4];                                       // B-frag: c = kf*16 + hi*8 + j
    {
        const _Float16* qr = qg + ((size_t)b * NN + Q0 + q32) * CC + hi * 8;
        #pragma unroll
        for (int kf = 0; kf < 4; ++kf) qf[kf] = *(const half8*)(qr + kf * 16);
    }
    const unsigned long long* Mrow = M + (size_t)(Q0 + q32) * 64 + c0;

    f32x16 o0 = {}, o1 = {};
    float m_run = 0.f, l_run = 0.f;

    stage(0, 0);
    unsigned long long cm = Mrow[0];
    __syncthreads();                      // drains vmcnt, then barrier

    for (int kc = 0; kc < 16; ++kc) {
        const int cur = kc & 1;
        unsigned long long pmn = 0;
        if (kc < 15) {
            stage(kc + 1, cur ^ 1);       // async into other buffer
            pmn = Mrow[kc + 1];
        }

        // ---- QK: S^T[key][qrow]
        const char* kbase = (const char*)&Kt[cur][0][0] + q32 * 128;
        __builtin_amdgcn_s_setprio(1);
        f32x16 s0 = {}, s1 = {};
        #pragma unroll
        for (int kf = 0; kf < 4; ++kf) {
            const int col = (kf * 32 + hi * 16) ^ swz;
            half8 ka0 = *(const half8*)(kbase + col);
            half8 ka1 = *(const half8*)(kbase + 4096 + col);
            s0 = __builtin_amdgcn_mfma_f32_32x32x16_f16(ka0, qf[kf], s0, 0, 0, 0);
            s1 = __builtin_amdgcn_mfma_f32_32x32x16_f16(ka1, qf[kf], s1, 0, 0, 0);
        }
        __builtin_amdgcn_s_setprio(0);

        const unsigned wlo = (unsigned)cm, whi = (unsigned)(cm >> 32);

        // ---- masked raw-score max: two running pkmax chains, masks
        // expanded on the fly (masked lanes AND to +0.0 == clamp-0)
        {
            unsigned run0 = 0u, run1 = 0u;
            #pragma unroll
            for (int a = 0; a < 4; ++a) {
                uint2 e0 = LUT[(wlo >> (8*a + 4*hi)) & 15u];
                uint2 e1 = LUT[(whi >> (8*a + 4*hi)) & 15u];
                run0 = pkmax(run0, pk_rtz(s0[4*a],   s0[4*a+1]) & e0.x);
                run0 = pkmax(run0, pk_rtz(s0[4*a+2], s0[4*a+3]) & e0.y);
                run1 = pkmax(run1, pk_rtz(s1[4*a],   s1[4*a+1]) & e1.x);
                run1 = pkmax(run1, pk_rtz(s1[4*a+2], s1[4*a+3]) & e1.y);
            }
            union { unsigned u; fp16x2 h; } tu; tu.u = pkmax(run0, run1);
            float mx = fmaxf((float)tu.h[0], (float)tu.h[1]);
            mx = fmaxf(mx, __shfl_xor(mx, 32));        // partner half
            if (__any(mx > m_run + 8.0f)) {            // defer-max THR=8
                float nm = fmaxf(m_run, mx);
                float alpha = __builtin_amdgcn_exp2f(m_run - nm);
                m_run = nm;
                l_run *= alpha;
                #pragma unroll
                for (int i = 0; i < 16; ++i) { o0[i] *= alpha; o1[i] *= alpha; }
            }
        }
        // ---- p = exp2(leaky(s) - m), pack + mask (masks re-expanded)
        unsigned wp[16];
        #pragma unroll
        for (int a = 0; a < 4; ++a) {
            uint2 e0 = LUT[(wlo >> (8*a + 4*hi)) & 15u];
            uint2 e1 = LUT[(whi >> (8*a + 4*hi)) & 15u];
            float p0 = __builtin_amdgcn_exp2f(fmaxf(s0[4*a]   - m_run, fmaf(0.01f, s0[4*a],   -m_run)));
            float p1 = __builtin_amdgcn_exp2f(fmaxf(s0[4*a+1] - m_run, fmaf(0.01f, s0[4*a+1], -m_run)));
            float p2 = __builtin_amdgcn_exp2f(fmaxf(s0[4*a+2] - m_run, fmaf(0.01f, s0[4*a+2], -m_run)));
            float p3 = __builtin_amdgcn_exp2f(fmaxf(s0[4*a+3] - m_run, fmaf(0.01f, s0[4*a+3], -m_run)));
            wp[2*a]   = pk_rtz(p0, p1) & e0.x;
            wp[2*a+1] = pk_rtz(p2, p3) & e0.y;
            float p4 = __builtin_amdgcn_exp2f(fmaxf(s1[4*a]   - m_run, fmaf(0.01f, s1[4*a],   -m_run)));
            float p5 = __builtin_amdgcn_exp2f(fmaxf(s1[4*a+1] - m_run, fmaf(0.01f, s1[4*a+1], -m_run)));
            float p6 = __builtin_amdgcn_exp2f(fmaxf(s1[4*a+2] - m_run, fmaf(0.01f, s1[4*a+2], -m_run)));
            float p7 = __builtin_amdgcn_exp2f(fmaxf(s1[4*a+3] - m_run, fmaf(0.01f, s1[4*a+3], -m_run)));
            wp[8+2*a]   = pk_rtz(p4, p5) & e1.x;
            wp[8+2*a+1] = pk_rtz(p6, p7) & e1.y;
        }
        // ---- l sum over own half (packed); pair-sum in epilogue
        {
            union { unsigned u; fp16x2 h; } z; z.u = 0u;
            fp16x2 acc = z.h;
            #pragma unroll
            for (int j4 = 0; j4 < 4; ++j4) {
                union { unsigned u; fp16x2 h; } x0, x1, x2, x3;
                x0.u = wp[4*j4]; x1.u = wp[4*j4+1]; x2.u = wp[4*j4+2]; x3.u = wp[4*j4+3];
                acc += (x0.h + x1.h) + (x2.h + x3.h);
            }
            l_run += (float)acc[0] + (float)acc[1];
        }
        // ---- redistribute P -> B-frag layout via shfl_xor(32)
        #pragma unroll
        for (int g4 = 0; g4 < 4; ++g4) {
            unsigned w0 = wp[4*g4+0], w1 = wp[4*g4+1];
            unsigned w2 = wp[4*g4+2], w3 = wp[4*g4+3];
            unsigned u = hi ? w0 : w2;
            unsigned v = hi ? w1 : w3;
            unsigned su = (unsigned)__shfl_xor((int)u, 32);
            unsigned sv = (unsigned)__shfl_xor((int)v, 32);
            wp[4*g4+0] = hi ? su : w0;
            wp[4*g4+1] = hi ? sv : w1;
            wp[4*g4+2] = hi ? w2 : su;
            wp[4*g4+3] = hi ? w3 : sv;
        }
        // ---- PV: O^T += V^T * P^T
        const char* vb = (const char*)&Vt[cur][0][0] + q32 * 128;
        __builtin_amdgcn_s_setprio(1);
        #pragma unroll
        for (int kc4 = 0; kc4 < 4; ++kc4) {
            union { unsigned u[4]; half8 h; } pb;
            pb.u[0] = wp[4*kc4+0]; pb.u[1] = wp[4*kc4+1];
            pb.u[2] = wp[4*kc4+2]; pb.u[3] = wp[4*kc4+3];
            const int col = (kc4 * 32 + hi * 16) ^ swz;
            half8 vf0 = *(const half8*)(vb + col);
            half8 vf1 = *(const half8*)(vb + 4096 + col);
            o0 = __builtin_amdgcn_mfma_f32_32x32x16_f16(vf0, pb.h, o0, 0, 0, 0);
            o1 = __builtin_amdgcn_mfma_f32_32x32x16_f16(vf1, pb.h, o1, 0, 0, 0);
        }
        __builtin_amdgcn_s_setprio(0);
        cm = pmn;
        if (kc < 15) __syncthreads();     // drains gll vmcnt + barrier
    }

    // epilogue: NORMALIZED fp16 partial o/l + (m, l) for combine
    float lt = l_run + __shfl_xor(l_run, 32);
    float invl = (lt > 0.f) ? 1.0f / lt : 0.f;
    size_t base = (size_t)sp * (BATCH * NN) + (size_t)b * NN + Q0 + q32;
    _Float16* orow = po + base * 64;
    #pragma unroll
    for (int a = 0; a < 4; ++a) {
        {
            uint2 ow = { pk_rtz(o0[4*a] * invl, o0[4*a+1] * invl),
                         pk_rtz(o0[4*a+2] * invl, o0[4*a+3] * invl) };
            *(uint2*)(orow + 8*a + 4*hi) = ow;
        }
        {
            uint2 ow = { pk_rtz(o1[4*a] * invl, o1[4*a+1] * invl),
                         pk_rtz(o1[4*a+2] * invl, o1[4*a+3] * invl) };
            *(uint2*)(orow + 32 + 8*a + 4*hi) = ow;
        }
    }
    if (hi == 0) pml[base] = make_float2(m_run, lt);
}

// ------------------------------------------------------------------
// Combine the 4 split-K partials (po holds NORMALIZED o/l):
// out = sum_s (w_s*l_s)*o_s / sum_s (w_s*l_s). 2048 blocks.
// ------------------------------------------------------------------
__global__ __launch_bounds__(256) void gat_comb(
    const _Float16* __restrict__ po, const float2* __restrict__ pml,
    float* __restrict__ out)
{
    int gid = blockIdx.x * 256 + threadIdx.x;     // 524288 threads
    int row = gid >> 4;                            // b*N + n
    int col = (gid & 15) * 4;
    float2 ml[4];
    float Mx = MASKV;
    #pragma unroll
    for (int s = 0; s < 4; ++s) {
        ml[s] = pml[s * (BATCH * NN) + row];
        Mx = fmaxf(Mx, ml[s].x);
    }
    float w[4], den = 0.f;
    #pragma unroll
    for (int s = 0; s < 4; ++s) {
        w[s] = __builtin_amdgcn_exp2f(ml[s].x - Mx) * ml[s].y;  // w_s * l_s
        den += w[s];
    }
    float inv = 1.0f / den;                        // diag guarantees den > 0
    float acc[4] = {};
    #pragma unroll
    for (int s = 0; s < 4; ++s) {
        const _Float16* p = po + ((size_t)s * (BATCH * NN) + row) * 64 + col;
        float a = w[s] * inv;
        half4 v = *(const half4*)(p);
        #pragma unroll
        for (int j = 0; j < 4; ++j) acc[j] += a * (float)v[j];
    }
    f32x4 r = {acc[0], acc[1], acc[2], acc[3]};
    *(f32x4*)(out + (size_t)row * 64 + col) = r;
}

extern "C" void kernel_launch(void* const* d_in, const int* in_sizes, int n_in,
                              void* d_out, int out_size, void* d_ws, size_t ws_size,
                              hipStream_t stream) {
    const float* X  = (const float*)d_in[0];
    const int*   A  = (const int*)d_in[1];
    const float* W0 = (const float*)d_in[2];
    const float* Wq = (const float*)d_in[3];
    const float* Wk = (const float*)d_in[4];
    float* out = (float*)d_out;
    char* ws = (char*)d_ws;
    const size_t SZ = (size_t)BATCH * NN * CC * 2;        // 4 MB per fp16 tensor
    _Float16* qh  = (_Float16*)(ws);
    _Float16* kbf = (_Float16*)(ws + SZ);
    _Float16* vtb = (_Float16*)(ws + 2*SZ);
    char* Mbase = ws + 3*SZ;                               // 2 MB mask
    _Float16* po = (_Float16*)(Mbase + 2*1024*1024);       // 16 MB
    float2* pml  = (float2*)(Mbase + 2*1024*1024 + 4*SZ);  // 1 MB

    hipLaunchKernelGGL(gat_prep, dim3(4608), dim3(256), 0, stream,
                       X, W0, Wq, Wk, A, qh, kbf, vtb, (unsigned short*)Mbase);
    hipLaunchKernelGGL(gat_attn, dim3(1024), dim3(256), 0, stream, qh, kbf, vtb,
                       (const unsigned long long*)Mbase, po, pml);
    hipLaunchKernelGGL(gat_comb, dim3(2048), dim3(256), 0, stream, po, pml, out);
}

// Round 12
// 183.901 us; speedup vs baseline: 1.3485x; 1.0217x over previous
//
#include <hip/hip_runtime.h>
#include <stdint.h>

#define BATCH 8
#define NN 4096
#define CC 64
#define MASKV -1.0e30f
#define LOG2E 1.4426950408889634f

typedef _Float16 half8 __attribute__((ext_vector_type(8)));
typedef _Float16 half4 __attribute__((ext_vector_type(4)));
typedef __fp16 fp16x2 __attribute__((ext_vector_type(2)));
typedef float f32x4 __attribute__((ext_vector_type(4)));
typedef float f32x16 __attribute__((ext_vector_type(16)));

typedef __attribute__((address_space(1))) const unsigned int gu32;
typedef __attribute__((address_space(3))) unsigned int lu32;
#define GLL16(gp, lp) __builtin_amdgcn_global_load_lds( \
    (gu32*)(uintptr_t)(gp), (lu32*)(unsigned)(uintptr_t)(lp), 16, 0, 0)

__device__ __forceinline__ unsigned pk_rtz(float a, float b) {
    union { fp16x2 h; unsigned u; } r;
    r.h = __builtin_amdgcn_cvt_pkrtz(a, b);
    return r.u;
}

// ------------------------------------------------------------------
// Fused prep: blocks 0-511 = projection (q fp16 pre-scaled by log2e,
// k fp16, vT fp16 [b][c][n]; split-compensated fp16 MFMA); blocks
// 512-4607 = adjacency bitmask (forced diagonal, compact 2 MB).
// ------------------------------------------------------------------
__global__ __launch_bounds__(256) void gat_prep(
    const float* __restrict__ X, const float* __restrict__ W0,
    const float* __restrict__ Wq, const float* __restrict__ Wk,
    const int* __restrict__ A,
    _Float16* __restrict__ qh, _Float16* __restrict__ kb,
    _Float16* __restrict__ vt, unsigned short* __restrict__ M16)
{
    __shared__ alignas(16) _Float16 WTh[3][64][72];
    __shared__ alignas(16) _Float16 WTl[3][64][72];
    const int t = threadIdx.x;
    if (blockIdx.x >= 512) {                       // ---- mask part
        const int row = blockIdx.x - 512;
        const int4* ap = (const int4*)(A + (size_t)row * NN + t * 16);
        unsigned m = 0;
        #pragma unroll
        for (int j = 0; j < 4; ++j) {
            int4 a = ap[j];
            m |= (a.x != 0 ? 1u : 0u) << (4*j);
            m |= (a.y != 0 ? 1u : 0u) << (4*j + 1);
            m |= (a.z != 0 ? 1u : 0u) << (4*j + 2);
            m |= (a.w != 0 ? 1u : 0u) << (4*j + 3);
        }
        if (t == (row >> 4)) m |= 1u << (row & 15);
        M16[(size_t)row * 256 + t] = (unsigned short)m;
        return;
    }
    // ---- projection part
    const float* Ws[3] = {W0, Wq, Wk};
    for (int e = t; e < 4096; e += 256) {
        int k = e >> 6, c = e & 63;
        #pragma unroll
        for (int m = 0; m < 3; ++m) {
            float w = Ws[m][e];
            _Float16 hi = (_Float16)w;
            WTh[m][c][k] = hi;
            WTl[m][c][k] = (_Float16)(w - (float)hi);
        }
    }
    __syncthreads();
    const int lane = t & 63, wv = t >> 6;
    const int cl = lane & 15, g = lane >> 4;
    int tile = blockIdx.x * 4 + wv;
    int gr = tile * 16;
    const float* xr = X + (size_t)(gr + cl) * CC;
    half8 xh[2], xl[2];
    #pragma unroll
    for (int kf = 0; kf < 2; ++kf) {
        f32x4 a0 = *(const f32x4*)(xr + g*8 + kf*32);
        f32x4 a1 = *(const f32x4*)(xr + g*8 + kf*32 + 4);
        half8 h, l;
        #pragma unroll
        for (int j = 0; j < 4; ++j) {
            _Float16 h0 = (_Float16)a0[j], h1 = (_Float16)a1[j];
            h[j]   = h0; l[j]   = (_Float16)(a0[j] - (float)h0);
            h[j+4] = h1; l[j+4] = (_Float16)(a1[j] - (float)h1);
        }
        xh[kf] = h; xl[kf] = l;
    }
    #pragma unroll
    for (int mat = 1; mat <= 2; ++mat) {
        #pragma unroll
        for (int nt = 0; nt < 4; ++nt) {
            f32x4 acc = {0.f, 0.f, 0.f, 0.f};
            #pragma unroll
            for (int kf = 0; kf < 2; ++kf) {
                half8 bh = *(const half8*)&WTh[mat][nt*16 + cl][g*8 + kf*32];
                half8 bl = *(const half8*)&WTl[mat][nt*16 + cl][g*8 + kf*32];
                acc = __builtin_amdgcn_mfma_f32_16x16x32_f16(xh[kf], bh, acc, 0, 0, 0);
                acc = __builtin_amdgcn_mfma_f32_16x16x32_f16(xl[kf], bh, acc, 0, 0, 0);
                acc = __builtin_amdgcn_mfma_f32_16x16x32_f16(xh[kf], bl, acc, 0, 0, 0);
            }
            #pragma unroll
            for (int i = 0; i < 4; ++i) {
                size_t off = (size_t)(gr + 4*g + i) * CC + nt*16 + cl;
                if (mat == 1) qh[off] = (_Float16)(acc[i] * LOG2E);
                else          kb[off] = (_Float16)acc[i];
            }
        }
    }
    {
        int b = gr >> 12, n0 = gr & (NN - 1);
        #pragma unroll
        for (int mt = 0; mt < 4; ++mt) {
            f32x4 acc = {0.f, 0.f, 0.f, 0.f};
            #pragma unroll
            for (int kf = 0; kf < 2; ++kf) {
                half8 ah = *(const half8*)&WTh[0][mt*16 + cl][g*8 + kf*32];
                half8 al = *(const half8*)&WTl[0][mt*16 + cl][g*8 + kf*32];
                acc = __builtin_amdgcn_mfma_f32_16x16x32_f16(ah, xh[kf], acc, 0, 0, 0);
                acc = __builtin_amdgcn_mfma_f32_16x16x32_f16(al, xh[kf], acc, 0, 0, 0);
                acc = __builtin_amdgcn_mfma_f32_16x16x32_f16(ah, xl[kf], acc, 0, 0, 0);
            }
            #pragma unroll
            for (int i = 0; i < 4; ++i) {
                int co = mt*16 + 4*g + i;
                vt[((size_t)b * CC + co) * NN + n0 + cl] = (_Float16)acc[i];
            }
        }
    }
}

// ------------------------------------------------------------------
// Flash attention, split-K x4 -- round-12: r11 (75us verified) with
// the softmax tail FUSED per 16-key group to cross the 4-waves/SIMD
// register cliff:
//  * r11 sat at 68 VGPR + 64 AGPR = 132 total -- 4 regs over the 128
//    band boundary (m69: waves halve at 64/128/256).
//  * wp[16] ELIMINATED: each P-word group g4 (4 words) is produced
//    (exp+pack+mask), l-accumulated, redistributed (2 shfl), and fed
//    to its PV MFMA pair in one phase -> peak P liveness 4 words.
//    PV MFMAs of phase g4 overlap the exp/pack VALU of phase g4+1.
//  * __launch_bounds__(256, 4) pins the 4-wave band; grid 1024 =
//    exactly 4 blocks/CU resident (LDS 33 KB allows 4), zero tail.
// ------------------------------------------------------------------
__global__ __launch_bounds__(256, 4) void gat_attn(
    const _Float16* __restrict__ qg,
    const _Float16* __restrict__ kf16, const _Float16* __restrict__ vtb,
    const unsigned long long* __restrict__ M,
    _Float16* __restrict__ po, float2* __restrict__ pml)
{
    __shared__ alignas(16) _Float16 Kt[2][64][64];    // [buf][key][c_in], swizzled
    __shared__ alignas(16) _Float16 Vt[2][64][64];    // [buf][c_out][key], swizzled
    __shared__ alignas(8) uint2 LUT[16];              // nib -> 2 halfword AND-masks
    const int t = threadIdx.x;
    const int lane = t & 63, wv = t >> 6;
    const int q32 = lane & 31, hi = lane >> 5;
    const int blk = blockIdx.x;        // 1024
    const int b  = blk & 7;            // batch == XCD
    const int sp = (blk >> 3) & 3;     // key split
    const int qb = blk >> 5;           // q tile 0..31
    const int Q0 = qb * 128 + wv * 32;
    const int c0 = sp * 16;
    const int swz = (q32 & 7) << 4;    // read-side XOR (row%8)

    if (t < 16) {
        unsigned n = t;
        LUT[n] = make_uint2(((n & 1u) ? 0x0000FFFFu : 0u) | ((n & 2u) ? 0xFFFF0000u : 0u),
                            ((n & 4u) ? 0x0000FFFFu : 0u) | ((n & 8u) ? 0xFFFF0000u : 0u));
    }

    // ---- async staging setup (wave wv owns one 4KB region)
    const int lrow = lane >> 3;                          // 0..7
    const int lcol = ((lane & 7) * 16) ^ (lrow << 4);    // pre-swizzled byte col
    const bool isK = (wv < 2);
    const int seg = isK ? wv : (wv - 2);
    const char* gsrc0 = isK
        ? (const char*)(kf16 + (size_t)b * NN * CC)
            + (size_t)c0 * 8192 + (size_t)seg * 4096 + lrow * 128 + lcol
        : (const char*)(vtb + (size_t)b * CC * NN)
            + (size_t)c0 * 128 + ((size_t)(seg * 32 + lrow)) * 8192 + lcol;
    const int istride = isK ? 1024 : 65536;
    const int cstride = isK ? 8192 : 128;

    auto stage = [&](int rel, int bufi) {
        const char* s = gsrc0 + (size_t)rel * cstride;
        char* d = isK ? ((char*)&Kt[bufi][0][0] + seg * 4096)
                      : ((char*)&Vt[bufi][0][0] + seg * 4096);
        #pragma unroll
        for (int i = 0; i < 4; ++i)
            GLL16(s + i * istride, d + i * 1024);
    };
    auto pkmax = [](unsigned a, unsigned b) {
        unsigned d;
        asm("v_pk_max_f16 %0, %1, %2" : "=v"(d) : "v"(a), "v"(b));
        return d;
    };

    half8 qf[4];                                       // B-frag: c = kf*16 + hi*8 + j
    {
        const _Float16* qr = qg + ((size_t)b * NN + Q0 + q32) * CC + hi * 8;
        #pragma unroll
        for (int kf = 0; kf < 4; ++kf) qf[kf] = *(const half8*)(qr + kf * 16);
    }
    const unsigned long long* Mrow = M + (size_t)(Q0 + q32) * 64 + c0;

    f32x16 o0 = {}, o1 = {};
    float m_run = 0.f, l_run = 0.f;

    stage(0, 0);
    unsigned long long cm = Mrow[0];
    __syncthreads();                      // drains vmcnt, then barrier

    for (int kc = 0; kc < 16; ++kc) {
        const int cur = kc & 1;
        unsigned long long pmn = 0;
        if (kc < 15) {
            stage(kc + 1, cur ^ 1);       // async into other buffer
            pmn = Mrow[kc + 1];
        }

        // ---- QK: S^T[key][qrow]
        const char* kbase = (const char*)&Kt[cur][0][0] + q32 * 128;
        __builtin_amdgcn_s_setprio(1);
        f32x16 s0 = {}, s1 = {};
        #pragma unroll
        for (int kf = 0; kf < 4; ++kf) {
            const int col = (kf * 32 + hi * 16) ^ swz;
            half8 ka0 = *(const half8*)(kbase + col);
            half8 ka1 = *(const half8*)(kbase + 4096 + col);
            s0 = __builtin_amdgcn_mfma_f32_32x32x16_f16(ka0, qf[kf], s0, 0, 0, 0);
            s1 = __builtin_amdgcn_mfma_f32_32x32x16_f16(ka1, qf[kf], s1, 0, 0, 0);
        }
        __builtin_amdgcn_s_setprio(0);

        const unsigned wlo = (unsigned)cm, whi = (unsigned)(cm >> 32);

        // ---- masked raw-score max: two running pkmax chains, masks
        // expanded on the fly (masked lanes AND to +0.0 == clamp-0)
        {
            unsigned run0 = 0u, run1 = 0u;
            #pragma unroll
            for (int a = 0; a < 4; ++a) {
                uint2 e0 = LUT[(wlo >> (8*a + 4*hi)) & 15u];
                uint2 e1 = LUT[(whi >> (8*a + 4*hi)) & 15u];
                run0 = pkmax(run0, pk_rtz(s0[4*a],   s0[4*a+1]) & e0.x);
                run0 = pkmax(run0, pk_rtz(s0[4*a+2], s0[4*a+3]) & e0.y);
                run1 = pkmax(run1, pk_rtz(s1[4*a],   s1[4*a+1]) & e1.x);
                run1 = pkmax(run1, pk_rtz(s1[4*a+2], s1[4*a+3]) & e1.y);
            }
            union { unsigned u; fp16x2 h; } tu; tu.u = pkmax(run0, run1);
            float mx = fmaxf((float)tu.h[0], (float)tu.h[1]);
            mx = fmaxf(mx, __shfl_xor(mx, 32));        // partner half
            if (__any(mx > m_run + 8.0f)) {            // defer-max THR=8
                float nm = fmaxf(m_run, mx);
                float alpha = __builtin_amdgcn_exp2f(m_run - nm);
                m_run = nm;
                l_run *= alpha;
                #pragma unroll
                for (int i = 0; i < 16; ++i) { o0[i] *= alpha; o1[i] *= alpha; }
            }
        }

        // ---- fused tail: per 16-key group g4 (== PV kc4):
        // exp+pack+mask -> l-acc -> redistribute (2 shfl) -> PV pair.
        // Only 4 P-words live at any time; PV(g4) overlaps exp(g4+1).
        const char* vb = (const char*)&Vt[cur][0][0] + q32 * 128;
        union UHH { unsigned u; fp16x2 h; };
        UHH zz; zz.u = 0u;
        fp16x2 lacc = zz.h;
        #pragma unroll
        for (int g4 = 0; g4 < 4; ++g4) {
            const unsigned wm = (g4 < 2) ? wlo : whi;
            const int a0 = (g4 & 1) * 2;
            unsigned w[4];
            #pragma unroll
            for (int aa = 0; aa < 2; ++aa) {
                const int a = a0 + aa;
                uint2 e = LUT[(wm >> (8*a + 4*hi)) & 15u];
                float x0, x1, x2, x3;
                if (g4 < 2) { x0 = s0[4*a]; x1 = s0[4*a+1]; x2 = s0[4*a+2]; x3 = s0[4*a+3]; }
                else        { x0 = s1[4*a]; x1 = s1[4*a+1]; x2 = s1[4*a+2]; x3 = s1[4*a+3]; }
                float p0 = __builtin_amdgcn_exp2f(fmaxf(x0 - m_run, fmaf(0.01f, x0, -m_run)));
                float p1 = __builtin_amdgcn_exp2f(fmaxf(x1 - m_run, fmaf(0.01f, x1, -m_run)));
                float p2 = __builtin_amdgcn_exp2f(fmaxf(x2 - m_run, fmaf(0.01f, x2, -m_run)));
                float p3 = __builtin_amdgcn_exp2f(fmaxf(x3 - m_run, fmaf(0.01f, x3, -m_run)));
                w[2*aa]   = pk_rtz(p0, p1) & e.x;
                w[2*aa+1] = pk_rtz(p2, p3) & e.y;
            }
            // l accumulation (packed)
            {
                UHH x0, x1, x2, x3;
                x0.u = w[0]; x1.u = w[1]; x2.u = w[2]; x3.u = w[3];
                lacc += (x0.h + x1.h) + (x2.h + x3.h);
            }
            // redistribute to B-frag layout via shfl_xor(32)
            unsigned u = hi ? w[0] : w[2];
            unsigned v = hi ? w[1] : w[3];
            unsigned su = (unsigned)__shfl_xor((int)u, 32);
            unsigned sv = (unsigned)__shfl_xor((int)v, 32);
            union { unsigned u[4]; half8 h; } pb;
            pb.u[0] = hi ? su : w[0];
            pb.u[1] = hi ? sv : w[1];
            pb.u[2] = hi ? w[2] : su;
            pb.u[3] = hi ? w[3] : sv;
            // PV: O^T += V^T[cols g4] * P^T[g4]
            const int col = (g4 * 32 + hi * 16) ^ swz;
            half8 vf0 = *(const half8*)(vb + col);
            half8 vf1 = *(const half8*)(vb + 4096 + col);
            __builtin_amdgcn_s_setprio(1);
            o0 = __builtin_amdgcn_mfma_f32_32x32x16_f16(vf0, pb.h, o0, 0, 0, 0);
            o1 = __builtin_amdgcn_mfma_f32_32x32x16_f16(vf1, pb.h, o1, 0, 0, 0);
            __builtin_amdgcn_s_setprio(0);
        }
        l_run += (float)lacc[0] + (float)lacc[1];

        cm = pmn;
        if (kc < 15) __syncthreads();     // drains gll vmcnt + barrier
    }

    // epilogue: NORMALIZED fp16 partial o/l + (m, l) for combine
    float lt = l_run + __shfl_xor(l_run, 32);
    float invl = (lt > 0.f) ? 1.0f / lt : 0.f;
    size_t base = (size_t)sp * (BATCH * NN) + (size_t)b * NN + Q0 + q32;
    _Float16* orow = po + base * 64;
    #pragma unroll
    for (int a = 0; a < 4; ++a) {
        {
            uint2 ow = { pk_rtz(o0[4*a] * invl, o0[4*a+1] * invl),
                         pk_rtz(o0[4*a+2] * invl, o0[4*a+3] * invl) };
            *(uint2*)(orow + 8*a + 4*hi) = ow;
        }
        {
            uint2 ow = { pk_rtz(o1[4*a] * invl, o1[4*a+1] * invl),
                         pk_rtz(o1[4*a+2] * invl, o1[4*a+3] * invl) };
            *(uint2*)(orow + 32 + 8*a + 4*hi) = ow;
        }
    }
    if (hi == 0) pml[base] = make_float2(m_run, lt);
}

// ------------------------------------------------------------------
// Combine the 4 split-K partials (po holds NORMALIZED o/l):
// out = sum_s (w_s*l_s)*o_s / sum_s (w_s*l_s). 2048 blocks.
// ------------------------------------------------------------------
__global__ __launch_bounds__(256) void gat_comb(
    const _Float16* __restrict__ po, const float2* __restrict__ pml,
    float* __restrict__ out)
{
    int gid = blockIdx.x * 256 + threadIdx.x;     // 524288 threads
    int row = gid >> 4;                            // b*N + n
    int col = (gid & 15) * 4;
    float2 ml[4];
    float Mx = MASKV;
    #pragma unroll
    for (int s = 0; s < 4; ++s) {
        ml[s] = pml[s * (BATCH * NN) + row];
        Mx = fmaxf(Mx, ml[s].x);
    }
    float w[4], den = 0.f;
    #pragma unroll
    for (int s = 0; s < 4; ++s) {
        w[s] = __builtin_amdgcn_exp2f(ml[s].x - Mx) * ml[s].y;  // w_s * l_s
        den += w[s];
    }
    float inv = 1.0f / den;                        // diag guarantees den > 0
    float acc[4] = {};
    #pragma unroll
    for (int s = 0; s < 4; ++s) {
        const _Float16* p = po + ((size_t)s * (BATCH * NN) + row) * 64 + col;
        float a = w[s] * inv;
        half4 v = *(const half4*)(p);
        #pragma unroll
        for (int j = 0; j < 4; ++j) acc[j] += a * (float)v[j];
    }
    f32x4 r = {acc[0], acc[1], acc[2], acc[3]};
    *(f32x4*)(out + (size_t)row * 64 + col) = r;
}

extern "C" void kernel_launch(void* const* d_in, const int* in_sizes, int n_in,
                              void* d_out, int out_size, void* d_ws, size_t ws_size,
                              hipStream_t stream) {
    const float* X  = (const float*)d_in[0];
    const int*   A  = (const int*)d_in[1];
    const float* W0 = (const float*)d_in[2];
    const float* Wq = (const float*)d_in[3];
    const float* Wk = (const float*)d_in[4];
    float* out = (float*)d_out;
    char* ws = (char*)d_ws;
    const size_t SZ = (size_t)BATCH * NN * CC * 2;        // 4 MB per fp16 tensor
    _Float16* qh  = (_Float16*)(ws);
    _Float16* kbf = (_Float16*)(ws + SZ);
    _Float16* vtb = (_Float16*)(ws + 2*SZ);
    char* Mbase = ws + 3*SZ;                               // 2 MB mask
    _Float16* po = (_Float16*)(Mbase + 2*1024*1024);       // 16 MB
    float2* pml  = (float2*)(Mbase + 2*1024*1024 + 4*SZ);  // 1 MB

    hipLaunchKernelGGL(gat_prep, dim3(4608), dim3(256), 0, stream,
                       X, W0, Wq, Wk, A, qh, kbf, vtb, (unsigned short*)Mbase);
    hipLaunchKernelGGL(gat_attn, dim3(1024), dim3(256), 0, stream, qh, kbf, vtb,
                       (const unsigned long long*)Mbase, po, pml);
    hipLaunchKernelGGL(gat_comb, dim3(2048), dim3(256), 0, stream, po, pml, out);
}